// Round 14
// baseline (21.520 us; speedup 1.0000x reference)
//
#include <hip/hip_runtime.h>
#include <hip/hip_bf16.h>

#define NPTS 1024
#define HID 128
#define KNN 10
#define PPB 2                  // points per block (block = PPB*256 threads)
#define FLT_MAX_ 3.402823466e+38f

// ---------------------------------------------------------------------------
// Kernel 1 (proven): build LUTs (epilogue folded) + repack points.
//   Td[v][c] = (sinusoid(v).Wd[c] + bd[c]) / 1024,  v in [0,256)
//   Ta[v][c] =  sinusoid(v).Wa[c] + ba[c],          v in [0,16)
//   P4[j]    = (x,y,z,0)
// grid: 272 blocks x 512 threads.
// ---------------------------------------------------------------------------
__global__ __launch_bounds__(512) void gse_build(
    const float* __restrict__ Wd, const float* __restrict__ bd,
    const float* __restrict__ Wa, const float* __restrict__ ba,
    const float* __restrict__ pts, int nP,
    float* __restrict__ Td, float* __restrict__ Ta, float4* __restrict__ P4) {
    const int blk = blockIdx.x;
    const int tid = threadIdx.x;

    if (tid < 8) {
        for (int idx = blk * 8 + tid; idx < nP; idx += 272 * 8) {
            P4[idx] = make_float4(pts[idx * 3 + 0], pts[idx * 3 + 1],
                                  pts[idx * 3 + 2], 0.0f);
        }
    }

    __shared__ float S[HID];
    __shared__ float part[512];
    const bool isA = (blk >= 256);
    const int v = isA ? blk - 256 : blk;
    const int c = tid & 127;
    const int seg = tid >> 7;               // 0..3

    if (tid < HID) {
        const int m = tid >> 1;
        const float dtm = expf((float)m * (float)(-9.210340371976184 / 64.0));
        const float arg = (float)v * dtm;
        S[tid] = (tid & 1) ? cosf(arg) : sinf(arg);
    }
    __syncthreads();

    const float* W = isA ? Wa : Wd;
    const float* wrow = W + c * HID + seg * 32;
    const float* srow = S + seg * 32;
    float acc = 0.0f;
    #pragma unroll
    for (int h = 0; h < 32; h += 4) {
        const float4 wv = *reinterpret_cast<const float4*>(wrow + h);
        acc += srow[h] * wv.x + srow[h + 1] * wv.y + srow[h + 2] * wv.z + srow[h + 3] * wv.w;
    }
    part[tid] = acc;
    __syncthreads();

    if (tid < HID) {
        const float s = (part[c] + part[c + 128]) + (part[c + 256] + part[c + 384]);
        if (isA) Ta[v * HID + c] = s + ba[c];
        else     Td[v * HID + c] = (s + bd[c]) * (1.0f / (float)NPTS);
    }
}

// ---------------------------------------------------------------------------
// Kernel 2: TWO points per block (512 threads = 2 x 4 waves), grid = nP/2.
//   R13 base + overlapped Td-dot:
//   segA (B3->B4): wave0 rank-select || waves1-3 dot, 3-way bin-interleave,
//                  float2 (2 channels/lane, ~13 iters each) -> pdot
//   segB (B4->B5): t<100 angles (fused unit-vector recompute)
//   epilogue: wave0 combines 3 pdot partials + 16 masked Ta float2 loads,
//             coalesced float2 store. No sums/mxs staging. 5 barriers.
//   Barriers live OUTSIDE the fast/fallback branch -> mixed points safe.
// ---------------------------------------------------------------------------
__global__ __launch_bounds__(512, 8) void gse_main2(
    const float4* __restrict__ P4,      // (nP)
    const float* __restrict__ Td,       // (256, 128)
    const float* __restrict__ Ta,       // (16, 128)
    float* __restrict__ out) {          // (nP, 128)
    const int tid = threadIdx.x;        // 0..511
    const int pt  = tid >> 8;           // 0..1  (point slot)
    const int t   = tid & 255;          // thread within point
    const int lane = tid & 63;
    const int w   = (tid >> 6) & 3;     // wave within point
    const int gid = blockIdx.x * PPB + pt;

    const int b = gid >> 10;
    const int i = gid & 1023;
    const float4* P = P4 + (size_t)b * NPTS;

    __shared__ int h4[PPB][4][256];
    __shared__ int hm[PPB][256];        // merged hist (for the dot)
    __shared__ unsigned long long cand[PPB][64];
    __shared__ int nn[PPB][KNN];
    __shared__ float2 pdot[PPB][3][64]; // 3-way dot partials (float2 = 2 ch)
    __shared__ unsigned amask_s[PPB];
    __shared__ int ccnt[PPB];
    __shared__ int meta_s[PPB];

    // ---- each wave zeroes its OWN hist slice (no barrier needed) ----
    #pragma unroll
    for (int k = 0; k < 4; ++k) h4[pt][w][lane + k * 64] = 0;
    if (t == 0) { amask_s[pt] = 0u; ccnt[pt] = 0; }
    const float4 p = P[i];

    // ---- phase 1: 4 distances/lane + per-wave private hist ----
    float d4[4];
    int q4[4];
    const int jb = w * 256;
    #pragma unroll
    for (int s = 0; s < 4; ++s) {
        const int j = jb + s * 64 + lane;
        const float4 q = P[j];
        const float dx = p.x - q.x;
        const float dy = p.y - q.y;
        const float dz = p.z - q.z;
        const float dd = sqrtf(dx * dx + dy * dy + dz * dz);
        d4[s] = dd;
        float qq = rintf(dd / 0.2f);    // matches jnp.round (half-to-even)
        qq = fminf(fmaxf(qq, 0.0f), 255.0f);
        q4[s] = (int)qq;
        atomicAdd(&h4[pt][w][q4[s]], 1);
    }
    __syncthreads();                                      // B1: hists done

    // ---- concurrent: wave0 scan/ballots (raw hists) || waves1-2 merge ----
    if (w == 0) {
        const int* H0 = h4[pt][0];
        const int* H1 = h4[pt][1];
        const int* H2 = h4[pt][2];
        const int* H3 = h4[pt][3];
        const int hv0 = H0[lane] + H1[lane] + H2[lane] + H3[lane];
        int cum = hv0;
        #pragma unroll
        for (int off = 1; off < 64; off <<= 1) {
            const int n_ = __shfl_up(cum, off);
            if (lane >= off) cum += n_;
        }
        const unsigned long long bal = __ballot(cum >= KNN);
        const int hv1 = H0[64 + lane] + H1[64 + lane] + H2[64 + lane] + H3[64 + lane];
        const int hv2 = H0[128 + lane] + H1[128 + lane] + H2[128 + lane] + H3[128 + lane];
        const int hv3 = H0[192 + lane] + H1[192 + lane] + H2[192 + lane] + H3[192 + lane];
        const unsigned long long nz0 = __ballot(hv0 != 0);
        const unsigned long long nz1 = __ballot(hv1 != 0);
        const unsigned long long nz2 = __ballot(hv2 != 0);
        const unsigned long long nz3 = __ballot(hv3 != 0);
        int maxbin;
        if (nz3)      maxbin = 192 + 63 - __clzll((long long)nz3);
        else if (nz2) maxbin = 128 + 63 - __clzll((long long)nz2);
        else if (nz1) maxbin = 64 + 63 - __clzll((long long)nz1);
        else          maxbin = 63 - __clzll((long long)nz0);
        int b10 = 0, c = 0;
        if (bal) { b10 = __ffsll(bal) - 1; c = __shfl(cum, b10); }
        const int fast = (bal != 0ull && c <= 64) ? 1 : 0;
        if (lane == 0) {
            meta_s[pt] = (b10 & 0xff) | ((fast ? c : 0) << 8)
                       | ((maxbin & 0xff) << 16) | (fast << 30);
        }
    } else if (w == 1) {
        #pragma unroll
        for (int k = 0; k < 2; ++k) {
            const int v = lane + k * 64;
            hm[pt][v] = h4[pt][0][v] + h4[pt][1][v] + h4[pt][2][v] + h4[pt][3][v];
        }
    } else if (w == 2) {
        #pragma unroll
        for (int k = 2; k < 4; ++k) {
            const int v = lane + k * 64;
            hm[pt][v] = h4[pt][0][v] + h4[pt][1][v] + h4[pt][2][v] + h4[pt][3][v];
        }
    }
    __syncthreads();                                      // B2: meta + hm ready
    const int meta = meta_s[pt];
    const int b10 = meta & 0xff;
    const int c = (meta >> 8) & 0xff;
    const int maxbin = (meta >> 16) & 0xff;
    const bool fast = ((meta >> 30) & 1) != 0;            // uniform per point

    if (fast) {
        // ---- ballot-base compaction of candidates (bin <= b10, c <= 64) ----
        #pragma unroll
        for (int s = 0; s < 4; ++s) {
            const bool pred = (q4[s] <= b10);
            const unsigned long long m = __ballot(pred);
            if (m) {
                int base = 0;
                if (lane == 0) base = atomicAdd(&ccnt[pt], __popcll(m));
                base = __shfl(base, 0);
                if (pred) {
                    const int pos = base + (int)__popcll(m & ((1ull << lane) - 1ull));
                    const int idx = jb + s * 64 + lane;
                    cand[pt][pos] = ((unsigned long long)__float_as_uint(d4[s]) << 32)
                                  | (unsigned)idx;
                }
            }
        }
    } else {
        // ---- fallback: per-wave top-10 into cand[pt][w*10..] ----
        unsigned valid = 0xfu;
        unsigned long long keep = 0;
        for (int r = 0; r < KNN; ++r) {
            float bv = FLT_MAX_;
            int bi = 0x7fffffff;
            #pragma unroll
            for (int s = 0; s < 4; ++s) {
                if (valid & (1u << s)) {
                    const float v_ = d4[s];
                    const int id_ = jb + s * 64 + lane;
                    if (v_ < bv || (v_ == bv && id_ < bi)) { bv = v_; bi = id_; }
                }
            }
            #pragma unroll
            for (int off = 32; off > 0; off >>= 1) {
                const float ov = __shfl_xor(bv, off);
                const int oi = __shfl_xor(bi, off);
                if (ov < bv || (ov == bv && oi < bi)) { bv = ov; bi = oi; }
            }
            const int loc = bi - jb;
            if (loc >= 0 && loc < 256 && lane == (loc & 63)) valid &= ~(1u << (loc >> 6));
            if (lane == r) keep = ((unsigned long long)__float_as_uint(bv) << 32)
                                | (unsigned)bi;
        }
        if (lane < KNN) cand[pt][w * KNN + lane] = keep;
    }
    __syncthreads();                                      // B3: cand staged

    // ---- segA: wave0 rank-select || waves1-3 3-way interleaved Td-dot ----
    const int ncand = fast ? c : 4 * KNN;
    if (w == 0) {
        if (t < ncand) {
            const unsigned long long my = cand[pt][t];
            int rank = 0;
            #pragma unroll 8
            for (int pp = 0; pp < ncand; ++pp) {
                rank += (cand[pt][pp] < my) ? 1 : 0;
            }
            if (rank < KNN) nn[pt][rank] = (int)(my & 0xffffffffu);
        }
    } else {
        const int k3 = w - 1;                             // 0..2
        const float2* td2 = reinterpret_cast<const float2*>(Td);
        float sx = 0.0f, sy = 0.0f;
        for (int v = k3; v <= maxbin; v += 3) {
            const float h = (float)hm[pt][v];             // uniform broadcast
            const float2 tv = td2[(size_t)v * 64 + lane]; // channels 2l,2l+1
            sx += h * tv.x;
            sy += h * tv.y;
        }
        pdot[pt][k3][lane] = make_float2(sx, sy);
    }
    __syncthreads();                                      // B4: nn + pdot ready

    // ---- segB: fused angles (per-pair unit-vector recompute) ----
    if (t < KNN * KNN) {
        const int k = t / KNN, l = t % KNN;
        const int jk = nn[pt][k], jl = nn[pt][l];
        const float4 qk = P[jk];
        const float4 ql = P[jl];
        const float kx = qk.x - p.x;
        const float ky = qk.y - p.y;
        const float kz = qk.z - p.z;
        const float dk = sqrtf(kx * kx + ky * ky + kz * kz) + 1e-8f;
        const float lx = ql.x - p.x;
        const float ly = ql.y - p.y;
        const float lz = ql.z - p.z;
        const float dl = sqrtf(lx * lx + ly * ly + lz * lz) + 1e-8f;
        float cc = (kx / dk) * (lx / dl) + (ky / dk) * (ly / dl) + (kz / dk) * (lz / dl);
        cc = fminf(fmaxf(cc, -1.0f), 1.0f);
        const float ang = acosf(cc);
        float q = rintf(ang * (float)(180.0 / (15.0 * M_PI)));
        q = fminf(fmaxf(q, 0.0f), 15.0f);
        atomicOr(&amask_s[pt], 1u << (int)q);
    }
    __syncthreads();                                      // B5: amask ready

    // ---- epilogue: wave0 combines partials + masked Ta max, float2 store ----
    if (w == 0) {
        const unsigned am = amask_s[pt];
        const float2 a0 = pdot[pt][0][lane];
        const float2 a1 = pdot[pt][1][lane];
        const float2 a2 = pdot[pt][2][lane];
        float sx = (a0.x + a1.x) + a2.x;
        float sy = (a0.y + a1.y) + a2.y;
        const float2* ta2 = reinterpret_cast<const float2*>(Ta);
        float mxx = -FLT_MAX_, mxy = -FLT_MAX_;
        #pragma unroll
        for (int v = 0; v < 16; ++v) {                    // unconditional loads
            const float2 tv = ta2[v * 64 + lane];
            if (am & (1u << v)) { mxx = fmaxf(mxx, tv.x); mxy = fmaxf(mxy, tv.y); }
        }
        float2* o2 = reinterpret_cast<float2*>(out + (size_t)gid * HID);
        o2[lane] = make_float2(sx + mxx, sy + mxy);       // 64 lanes x 8B
    }
}

// ---------------------------------------------------------------------------
// Fallback single-point kernel (R13, proven) for nP not divisible by PPB.
// ---------------------------------------------------------------------------
__global__ __launch_bounds__(256, 8) void gse_main(
    const float4* __restrict__ P4,
    const float* __restrict__ Td,
    const float* __restrict__ Ta,
    float* __restrict__ out) {
    const int gid = blockIdx.x;
    const int b = gid >> 10;
    const int i = gid & 1023;
    const float4* P = P4 + (size_t)b * NPTS;
    const int tid = threadIdx.x;
    const int lane = tid & 63;
    const int w = tid >> 6;

    __shared__ int h4[4][256];
    __shared__ unsigned long long cand[64];
    __shared__ int nn[KNN];
    __shared__ float sums[256], mxs[256];
    __shared__ unsigned amask_s;
    __shared__ int ccnt;
    __shared__ int meta_s;

    {
        int* hf = (int*)h4;
        hf[tid] = 0; hf[tid + 256] = 0; hf[tid + 512] = 0; hf[tid + 768] = 0;
    }
    if (tid == 0) { amask_s = 0u; ccnt = 0; }
    const float4 p = P[i];
    __syncthreads();

    float d4[4];
    int q4[4];
    const int jb = w * 256;
    #pragma unroll
    for (int s = 0; s < 4; ++s) {
        const int j = jb + s * 64 + lane;
        const float4 q = P[j];
        const float dx = p.x - q.x;
        const float dy = p.y - q.y;
        const float dz = p.z - q.z;
        const float dd = sqrtf(dx * dx + dy * dy + dz * dz);
        d4[s] = dd;
        float qq = rintf(dd / 0.2f);
        qq = fminf(fmaxf(qq, 0.0f), 255.0f);
        q4[s] = (int)qq;
        atomicAdd(&h4[w][q4[s]], 1);
    }
    __syncthreads();

    const int hsum = h4[0][tid] + h4[1][tid] + h4[2][tid] + h4[3][tid];
    h4[0][tid] = hsum;
    __syncthreads();
    const int* hist = h4[0];

    if (w == 0) {
        int cum = hist[lane];
        #pragma unroll
        for (int off = 1; off < 64; off <<= 1) {
            const int n_ = __shfl_up(cum, off);
            if (lane >= off) cum += n_;
        }
        const unsigned long long bal = __ballot(cum >= KNN);
        const unsigned long long nz0 = __ballot(hist[lane] != 0);
        const unsigned long long nz1 = __ballot(hist[64 + lane] != 0);
        const unsigned long long nz2 = __ballot(hist[128 + lane] != 0);
        const unsigned long long nz3 = __ballot(hist[192 + lane] != 0);
        int maxbin;
        if (nz3)      maxbin = 192 + 63 - __clzll((long long)nz3);
        else if (nz2) maxbin = 128 + 63 - __clzll((long long)nz2);
        else if (nz1) maxbin = 64 + 63 - __clzll((long long)nz1);
        else          maxbin = 63 - __clzll((long long)nz0);
        int b10 = 0, c = 0;
        if (bal) { b10 = __ffsll(bal) - 1; c = __shfl(cum, b10); }
        const int fast = (bal != 0ull && c <= 64) ? 1 : 0;
        if (lane == 0) {
            meta_s = (b10 & 0xff) | ((fast ? c : 0) << 8)
                   | ((maxbin & 0xff) << 16) | (fast << 30);
        }
    }
    __syncthreads();
    const int meta = meta_s;
    const int b10 = meta & 0xff;
    const int c = (meta >> 8) & 0xff;
    const int maxbin = (meta >> 16) & 0xff;
    const bool fast = ((meta >> 30) & 1) != 0;

    if (fast) {
        #pragma unroll
        for (int s = 0; s < 4; ++s) {
            const bool pred = (q4[s] <= b10);
            const unsigned long long m = __ballot(pred);
            if (m) {
                int base = 0;
                if (lane == 0) base = atomicAdd(&ccnt, __popcll(m));
                base = __shfl(base, 0);
                if (pred) {
                    const int pos = base + (int)__popcll(m & ((1ull << lane) - 1ull));
                    const int idx = jb + s * 64 + lane;
                    cand[pos] = ((unsigned long long)__float_as_uint(d4[s]) << 32)
                              | (unsigned)idx;
                }
            }
        }
        __syncthreads();
        if (tid < c) {
            const unsigned long long my = cand[tid];
            int rank = 0;
            #pragma unroll 8
            for (int pp = 0; pp < c; ++pp) rank += (cand[pp] < my) ? 1 : 0;
            if (rank < KNN) nn[rank] = (int)(my & 0xffffffffu);
        }
        __syncthreads();
    } else {
        unsigned valid = 0xfu;
        unsigned long long keep = 0;
        for (int r = 0; r < KNN; ++r) {
            float bv = FLT_MAX_;
            int bi = 0x7fffffff;
            #pragma unroll
            for (int s = 0; s < 4; ++s) {
                if (valid & (1u << s)) {
                    const float v_ = d4[s];
                    const int id_ = jb + s * 64 + lane;
                    if (v_ < bv || (v_ == bv && id_ < bi)) { bv = v_; bi = id_; }
                }
            }
            #pragma unroll
            for (int off = 32; off > 0; off >>= 1) {
                const float ov = __shfl_xor(bv, off);
                const int oi = __shfl_xor(bi, off);
                if (ov < bv || (ov == bv && oi < bi)) { bv = ov; bi = oi; }
            }
            const int loc = bi - jb;
            if (loc >= 0 && loc < 256 && lane == (loc & 63)) valid &= ~(1u << (loc >> 6));
            if (lane == r) keep = ((unsigned long long)__float_as_uint(bv) << 32)
                                | (unsigned)bi;
        }
        if (lane < KNN) cand[w * KNN + lane] = keep;
        __syncthreads();
        if (tid < 4 * KNN) {
            const unsigned long long my = cand[tid];
            int rank = 0;
            for (int pp = 0; pp < 4 * KNN; ++pp) rank += (cand[pp] < my) ? 1 : 0;
            if (rank < KNN) nn[rank] = (int)(my & 0xffffffffu);
        }
        __syncthreads();
    }

    if (tid < KNN * KNN) {
        const int k = tid / KNN, l = tid % KNN;
        const int jk = nn[k], jl = nn[l];
        const float4 qk = P[jk];
        const float4 ql = P[jl];
        const float kx = qk.x - p.x;
        const float ky = qk.y - p.y;
        const float kz = qk.z - p.z;
        const float dk = sqrtf(kx * kx + ky * ky + kz * kz) + 1e-8f;
        const float lx = ql.x - p.x;
        const float ly = ql.y - p.y;
        const float lz = ql.z - p.z;
        const float dl = sqrtf(lx * lx + ly * ly + lz * lz) + 1e-8f;
        float cc = (kx / dk) * (lx / dl) + (ky / dk) * (ly / dl) + (kz / dk) * (lz / dl);
        cc = fminf(fmaxf(cc, -1.0f), 1.0f);
        const float ang = acosf(cc);
        float q = rintf(ang * (float)(180.0 / (15.0 * M_PI)));
        q = fminf(fmaxf(q, 0.0f), 15.0f);
        atomicOr(&amask_s, 1u << (int)q);
    }
    __syncthreads();

    const unsigned am = amask_s;
    const int c7 = tid & 127;
    const int half = tid >> 7;
    float s = 0.0f;
    const float* tdc = Td + c7;
    #pragma unroll 4
    for (int v = half; v <= maxbin; v += 2) {
        s += (float)hist[v] * tdc[v * HID];
    }
    float mx = -FLT_MAX_;
    const float* tac = Ta + c7;
    #pragma unroll
    for (int v = 0; v < 8; ++v) {
        const int vv = half * 8 + v;
        const float tv = tac[vv * HID];
        if (am & (1u << vv)) mx = fmaxf(mx, tv);
    }
    sums[tid] = s;
    mxs[tid] = mx;
    __syncthreads();
    if (tid < HID) {
        out[(size_t)gid * HID + tid] =
            (sums[tid] + sums[tid + 128]) + fmaxf(mxs[tid], mxs[tid + 128]);
    }
}

extern "C" void kernel_launch(void* const* d_in, const int* in_sizes, int n_in,
                              void* d_out, int out_size, void* d_ws, size_t ws_size,
                              hipStream_t stream) {
    const float* pts = (const float*)d_in[0];
    const float* Wd  = (const float*)d_in[1];
    const float* bd  = (const float*)d_in[2];
    const float* Wa  = (const float*)d_in[3];
    const float* ba  = (const float*)d_in[4];
    float* out = (float*)d_out;

    const int B = in_sizes[0] / (NPTS * 3);
    const int nP = B * NPTS;

    float* Td = (float*)d_ws;                        // 256*128*4 = 128 KiB
    float* Ta = Td + 256 * HID;                      // 16*128*4  =   8 KiB
    float4* P4 = (float4*)(Ta + 16 * HID);           // nP*16 B

    gse_build<<<272, 512, 0, stream>>>(Wd, bd, Wa, ba, pts, nP, Td, Ta, P4);
    if (nP % PPB == 0) {
        gse_main2<<<nP / PPB, PPB * 256, 0, stream>>>(P4, Td, Ta, out);
    } else {
        gse_main<<<nP, 256, 0, stream>>>(P4, Td, Ta, out);
    }
}

// Round 15
// 19.952 us; speedup vs baseline: 1.0786x; 1.0786x over previous
//
#include <hip/hip_runtime.h>
#include <hip/hip_bf16.h>

#define NPTS 1024
#define HID 128
#define KNN 10
#define PPB 2                  // points per block (block = PPB*256 threads)
#define FLT_MAX_ 3.402823466e+38f

// ---------------------------------------------------------------------------
// Kernel 1: build LUTs (epilogue folded) + repack points (strided).
//   Td[v][c] = (sinusoid(v).Wd[c] + bd[c]) / 1024,  v in [0,256)
//   Ta[v][c] =  sinusoid(v).Wa[c] + ba[c],          v in [0,16)
//   P4[j]    = (x,y,z,0)
// grid: 272 blocks x 512 threads.
// ---------------------------------------------------------------------------
__global__ __launch_bounds__(512) void gse_build(
    const float* __restrict__ Wd, const float* __restrict__ bd,
    const float* __restrict__ Wa, const float* __restrict__ ba,
    const float* __restrict__ pts, int nP,
    float* __restrict__ Td, float* __restrict__ Ta, float4* __restrict__ P4) {
    const int blk = blockIdx.x;
    const int tid = threadIdx.x;

    // folded repack: 8 points per block per pass, strided for any nP
    if (tid < 8) {
        for (int idx = blk * 8 + tid; idx < nP; idx += 272 * 8) {
            P4[idx] = make_float4(pts[idx * 3 + 0], pts[idx * 3 + 1],
                                  pts[idx * 3 + 2], 0.0f);
        }
    }

    __shared__ float S[HID];
    __shared__ float part[512];
    const bool isA = (blk >= 256);
    const int v = isA ? blk - 256 : blk;
    const int c = tid & 127;
    const int seg = tid >> 7;               // 0..3

    if (tid < HID) {
        const int m = tid >> 1;
        const float dtm = expf((float)m * (float)(-9.210340371976184 / 64.0));
        const float arg = (float)v * dtm;
        S[tid] = (tid & 1) ? cosf(arg) : sinf(arg);
    }
    __syncthreads();

    const float* W = isA ? Wa : Wd;
    const float* wrow = W + c * HID + seg * 32;
    const float* srow = S + seg * 32;
    float acc = 0.0f;
    #pragma unroll
    for (int h = 0; h < 32; h += 4) {
        const float4 wv = *reinterpret_cast<const float4*>(wrow + h);
        acc += srow[h] * wv.x + srow[h + 1] * wv.y + srow[h + 2] * wv.z + srow[h + 3] * wv.w;
    }
    part[tid] = acc;
    __syncthreads();

    if (tid < HID) {
        const float s = (part[c] + part[c + 128]) + (part[c + 256] + part[c + 384]);
        if (isA) Ta[v * HID + c] = s + ba[c];
        else     Td[v * HID + c] = (s + bd[c]) * (1.0f / (float)NPTS);
    }
}

// ---------------------------------------------------------------------------
// Kernel 2 (R10, the measured optimum at 20.13us): TWO points per block
// (512 threads = 2 x 4 waves), grid = nP/2 -> 1024 WGs, 4 blocks/CU x 8
// waves = 32 waves/CU (100%). Candidates packed as u64 (fbits(d)<<32 | idx):
// positive-float bit order is monotonic, so ONE 64-bit compare = exact
// (d, idx) lexicographic rank. Barrier parity between fast/fallback.
// ---------------------------------------------------------------------------
__global__ __launch_bounds__(512, 8) void gse_main2(
    const float4* __restrict__ P4,      // (nP)
    const float* __restrict__ Td,       // (256, 128)
    const float* __restrict__ Ta,       // (16, 128)
    float* __restrict__ out) {          // (nP, 128)
    const int tid = threadIdx.x;        // 0..511
    const int pt  = tid >> 8;           // 0..1  (point slot)
    const int t   = tid & 255;          // thread within point
    const int lane = tid & 63;
    const int w   = (tid >> 6) & 3;     // wave within point
    const int gid = blockIdx.x * PPB + pt;

    const int b = gid >> 10;
    const int i = gid & 1023;
    const float4* P = P4 + (size_t)b * NPTS;

    __shared__ int h4[PPB][4][256];
    __shared__ unsigned long long cand[PPB][64];
    __shared__ int nn[PPB][KNN];
    __shared__ float uxs[PPB][KNN], uys[PPB][KNN], uzs[PPB][KNN];
    __shared__ float sums[PPB][256], mxs[PPB][256];
    __shared__ unsigned amask_s[PPB];
    __shared__ int ccnt[PPB];
    __shared__ int meta_s[PPB];

    {   // zero my point's hist (1024 ints over 256 threads)
        int* hf = (int*)h4[pt];
        hf[t] = 0; hf[t + 256] = 0; hf[t + 512] = 0; hf[t + 768] = 0;
    }
    if (t == 0) { amask_s[pt] = 0u; ccnt[pt] = 0; }
    const float4 p = P[i];
    __syncthreads();                                      // B1

    // ---- phase 1: 4 distances/lane + per-wave private hist ----
    float d4[4];
    int q4[4];
    const int jb = w * 256;
    #pragma unroll
    for (int s = 0; s < 4; ++s) {
        const int j = jb + s * 64 + lane;
        const float4 q = P[j];
        const float dx = p.x - q.x;
        const float dy = p.y - q.y;
        const float dz = p.z - q.z;
        const float dd = sqrtf(dx * dx + dy * dy + dz * dz);
        d4[s] = dd;
        float qq = rintf(dd / 0.2f);    // matches jnp.round (half-to-even)
        qq = fminf(fmaxf(qq, 0.0f), 255.0f);
        q4[s] = (int)qq;
        atomicAdd(&h4[pt][w][q4[s]], 1);
    }
    __syncthreads();                                      // B2

    // ---- merge the 4 per-wave hists ----
    const int hsum = h4[pt][0][t] + h4[pt][1][t] + h4[pt][2][t] + h4[pt][3][t];
    h4[pt][0][t] = hsum;
    __syncthreads();                                      // B3
    const int* hist = h4[pt][0];

    // ---- wave 0 (of each point): scan bins 0..63 + ballots -> meta ----
    if (w == 0) {
        int cum = hist[lane];
        #pragma unroll
        for (int off = 1; off < 64; off <<= 1) {
            const int n_ = __shfl_up(cum, off);
            if (lane >= off) cum += n_;
        }
        const unsigned long long bal = __ballot(cum >= KNN);
        const unsigned long long nz0 = __ballot(hist[lane] != 0);
        const unsigned long long nz1 = __ballot(hist[64 + lane] != 0);
        const unsigned long long nz2 = __ballot(hist[128 + lane] != 0);
        const unsigned long long nz3 = __ballot(hist[192 + lane] != 0);
        int maxbin;
        if (nz3)      maxbin = 192 + 63 - __clzll((long long)nz3);
        else if (nz2) maxbin = 128 + 63 - __clzll((long long)nz2);
        else if (nz1) maxbin = 64 + 63 - __clzll((long long)nz1);
        else          maxbin = 63 - __clzll((long long)nz0);
        int b10 = 0, c = 0;
        if (bal) { b10 = __ffsll(bal) - 1; c = __shfl(cum, b10); }
        const int fast = (bal != 0ull && c <= 64) ? 1 : 0;
        if (lane == 0) {
            meta_s[pt] = (b10 & 0xff) | ((fast ? c : 0) << 8)
                       | ((maxbin & 0xff) << 16) | (fast << 30);
        }
    }
    __syncthreads();                                      // B4
    const int meta = meta_s[pt];
    const int b10 = meta & 0xff;
    const int c = (meta >> 8) & 0xff;
    const int maxbin = (meta >> 16) & 0xff;
    const bool fast = ((meta >> 30) & 1) != 0;            // uniform per point

    if (fast) {
        // ---- ballot-base compaction of candidates (bin <= b10, c <= 64) ----
        #pragma unroll
        for (int s = 0; s < 4; ++s) {
            const bool pred = (q4[s] <= b10);
            const unsigned long long m = __ballot(pred);
            if (m) {
                int base = 0;
                if (lane == 0) base = atomicAdd(&ccnt[pt], __popcll(m));
                base = __shfl(base, 0);
                if (pred) {
                    const int pos = base + (int)__popcll(m & ((1ull << lane) - 1ull));
                    const int idx = jb + s * 64 + lane;
                    cand[pt][pos] = ((unsigned long long)__float_as_uint(d4[s]) << 32)
                                  | (unsigned)idx;
                }
            }
        }
        __syncthreads();                                  // B5
        if (t < c) {
            const unsigned long long my = cand[pt][t];
            int rank = 0;
            #pragma unroll 8
            for (int pp = 0; pp < c; ++pp) {
                rank += (cand[pt][pp] < my) ? 1 : 0;
            }
            if (rank < KNN) nn[pt][rank] = (int)(my & 0xffffffffu);
        }
        __syncthreads();                                  // B6
    } else {
        // ---- fallback: per-wave top-10, then 40-way u64 rank merge ----
        unsigned valid = 0xfu;
        unsigned long long keep = 0;
        for (int r = 0; r < KNN; ++r) {
            float bv = FLT_MAX_;
            int bi = 0x7fffffff;
            #pragma unroll
            for (int s = 0; s < 4; ++s) {
                if (valid & (1u << s)) {
                    const float v_ = d4[s];
                    const int id_ = jb + s * 64 + lane;
                    if (v_ < bv || (v_ == bv && id_ < bi)) { bv = v_; bi = id_; }
                }
            }
            #pragma unroll
            for (int off = 32; off > 0; off >>= 1) {
                const float ov = __shfl_xor(bv, off);
                const int oi = __shfl_xor(bi, off);
                if (ov < bv || (ov == bv && oi < bi)) { bv = ov; bi = oi; }
            }
            const int loc = bi - jb;
            if (loc >= 0 && loc < 256 && lane == (loc & 63)) valid &= ~(1u << (loc >> 6));
            if (lane == r) keep = ((unsigned long long)__float_as_uint(bv) << 32)
                                | (unsigned)bi;
        }
        if (lane < KNN) cand[pt][w * KNN + lane] = keep;
        __syncthreads();                                  // B5
        if (t < 4 * KNN) {
            const unsigned long long my = cand[pt][t];
            int rank = 0;
            for (int pp = 0; pp < 4 * KNN; ++pp) {
                rank += (cand[pt][pp] < my) ? 1 : 0;
            }
            if (rank < KNN) nn[pt][rank] = (int)(my & 0xffffffffu);
        }
        __syncthreads();                                  // B6
    }

    // ---- phase 3: unit vectors ----
    if (t < KNN) {
        const float4 qn = P[nn[pt][t]];
        const float vx = qn.x - p.x;
        const float vy = qn.y - p.y;
        const float vz = qn.z - p.z;
        const float den = sqrtf(vx * vx + vy * vy + vz * vz) + 1e-8f;
        uxs[pt][t] = vx / den; uys[pt][t] = vy / den; uzs[pt][t] = vz / den;
    }
    __syncthreads();                                      // B7

    // ---- phase 4: 100 pairwise angles -> presence mask ----
    if (t < KNN * KNN) {
        const int k = t / KNN, l = t % KNN;
        float cc = uxs[pt][k] * uxs[pt][l] + uys[pt][k] * uys[pt][l]
                 + uzs[pt][k] * uzs[pt][l];
        cc = fminf(fmaxf(cc, -1.0f), 1.0f);
        const float ang = acosf(cc);
        float q = rintf(ang * (float)(180.0 / (15.0 * M_PI)));
        q = fminf(fmaxf(q, 0.0f), 15.0f);
        atomicOr(&amask_s[pt], 1u << (int)q);
    }
    __syncthreads();                                      // B8

    // ---- phase 5: split even/odd bins + low/high mask across half-points ----
    const unsigned am = amask_s[pt];
    const int c7 = t & 127;
    const int half = t >> 7;
    float s = 0.0f;
    const float* tdc = Td + c7;
    #pragma unroll 4
    for (int v = half; v <= maxbin; v += 2) {
        s += (float)hist[v] * tdc[v * HID];   // zero bins add exact 0.0f
    }
    float mx = -FLT_MAX_;
    const float* tac = Ta + c7;
    #pragma unroll
    for (int v = 0; v < 8; ++v) {
        const int vv = half * 8 + v;
        const float tv = tac[vv * HID];
        if (am & (1u << vv)) mx = fmaxf(mx, tv);
    }
    sums[pt][t] = s;
    mxs[pt][t] = mx;
    __syncthreads();                                      // B9
    if (t < HID) {
        out[(size_t)gid * HID + t] =
            (sums[pt][t] + sums[pt][t + 128]) + fmaxf(mxs[pt][t], mxs[pt][t + 128]);
    }
}

// ---------------------------------------------------------------------------
// Fallback single-point kernel (proven) for nP not divisible by PPB.
// ---------------------------------------------------------------------------
__global__ __launch_bounds__(256, 8) void gse_main(
    const float4* __restrict__ P4,
    const float* __restrict__ Td,
    const float* __restrict__ Ta,
    float* __restrict__ out) {
    const int gid = blockIdx.x;
    const int b = gid >> 10;
    const int i = gid & 1023;
    const float4* P = P4 + (size_t)b * NPTS;
    const int tid = threadIdx.x;
    const int lane = tid & 63;
    const int w = tid >> 6;

    __shared__ int h4[4][256];
    __shared__ unsigned long long cand[64];
    __shared__ int nn[KNN];
    __shared__ float uxs[KNN], uys[KNN], uzs[KNN];
    __shared__ float sums[256], mxs[256];
    __shared__ unsigned amask_s;
    __shared__ int ccnt;
    __shared__ int meta_s;

    {
        int* hf = (int*)h4;
        hf[tid] = 0; hf[tid + 256] = 0; hf[tid + 512] = 0; hf[tid + 768] = 0;
    }
    if (tid == 0) { amask_s = 0u; ccnt = 0; }
    const float4 p = P[i];
    __syncthreads();

    float d4[4];
    int q4[4];
    const int jb = w * 256;
    #pragma unroll
    for (int s = 0; s < 4; ++s) {
        const int j = jb + s * 64 + lane;
        const float4 q = P[j];
        const float dx = p.x - q.x;
        const float dy = p.y - q.y;
        const float dz = p.z - q.z;
        const float dd = sqrtf(dx * dx + dy * dy + dz * dz);
        d4[s] = dd;
        float qq = rintf(dd / 0.2f);
        qq = fminf(fmaxf(qq, 0.0f), 255.0f);
        q4[s] = (int)qq;
        atomicAdd(&h4[w][q4[s]], 1);
    }
    __syncthreads();

    const int hsum = h4[0][tid] + h4[1][tid] + h4[2][tid] + h4[3][tid];
    h4[0][tid] = hsum;
    __syncthreads();
    const int* hist = h4[0];

    if (w == 0) {
        int cum = hist[lane];
        #pragma unroll
        for (int off = 1; off < 64; off <<= 1) {
            const int n_ = __shfl_up(cum, off);
            if (lane >= off) cum += n_;
        }
        const unsigned long long bal = __ballot(cum >= KNN);
        const unsigned long long nz0 = __ballot(hist[lane] != 0);
        const unsigned long long nz1 = __ballot(hist[64 + lane] != 0);
        const unsigned long long nz2 = __ballot(hist[128 + lane] != 0);
        const unsigned long long nz3 = __ballot(hist[192 + lane] != 0);
        int maxbin;
        if (nz3)      maxbin = 192 + 63 - __clzll((long long)nz3);
        else if (nz2) maxbin = 128 + 63 - __clzll((long long)nz2);
        else if (nz1) maxbin = 64 + 63 - __clzll((long long)nz1);
        else          maxbin = 63 - __clzll((long long)nz0);
        int b10 = 0, c = 0;
        if (bal) { b10 = __ffsll(bal) - 1; c = __shfl(cum, b10); }
        const int fast = (bal != 0ull && c <= 64) ? 1 : 0;
        if (lane == 0) {
            meta_s = (b10 & 0xff) | ((fast ? c : 0) << 8)
                   | ((maxbin & 0xff) << 16) | (fast << 30);
        }
    }
    __syncthreads();
    const int meta = meta_s;
    const int b10 = meta & 0xff;
    const int c = (meta >> 8) & 0xff;
    const int maxbin = (meta >> 16) & 0xff;
    const bool fast = ((meta >> 30) & 1) != 0;

    if (fast) {
        #pragma unroll
        for (int s = 0; s < 4; ++s) {
            const bool pred = (q4[s] <= b10);
            const unsigned long long m = __ballot(pred);
            if (m) {
                int base = 0;
                if (lane == 0) base = atomicAdd(&ccnt, __popcll(m));
                base = __shfl(base, 0);
                if (pred) {
                    const int pos = base + (int)__popcll(m & ((1ull << lane) - 1ull));
                    const int idx = jb + s * 64 + lane;
                    cand[pos] = ((unsigned long long)__float_as_uint(d4[s]) << 32)
                              | (unsigned)idx;
                }
            }
        }
        __syncthreads();
        if (tid < c) {
            const unsigned long long my = cand[tid];
            int rank = 0;
            #pragma unroll 8
            for (int pp = 0; pp < c; ++pp) rank += (cand[pp] < my) ? 1 : 0;
            if (rank < KNN) nn[rank] = (int)(my & 0xffffffffu);
        }
        __syncthreads();
    } else {
        unsigned valid = 0xfu;
        unsigned long long keep = 0;
        for (int r = 0; r < KNN; ++r) {
            float bv = FLT_MAX_;
            int bi = 0x7fffffff;
            #pragma unroll
            for (int s = 0; s < 4; ++s) {
                if (valid & (1u << s)) {
                    const float v_ = d4[s];
                    const int id_ = jb + s * 64 + lane;
                    if (v_ < bv || (v_ == bv && id_ < bi)) { bv = v_; bi = id_; }
                }
            }
            #pragma unroll
            for (int off = 32; off > 0; off >>= 1) {
                const float ov = __shfl_xor(bv, off);
                const int oi = __shfl_xor(bi, off);
                if (ov < bv || (ov == bv && oi < bi)) { bv = ov; bi = oi; }
            }
            const int loc = bi - jb;
            if (loc >= 0 && loc < 256 && lane == (loc & 63)) valid &= ~(1u << (loc >> 6));
            if (lane == r) keep = ((unsigned long long)__float_as_uint(bv) << 32)
                                | (unsigned)bi;
        }
        if (lane < KNN) cand[w * KNN + lane] = keep;
        __syncthreads();
        if (tid < 4 * KNN) {
            const unsigned long long my = cand[tid];
            int rank = 0;
            for (int pp = 0; pp < 4 * KNN; ++pp) rank += (cand[pp] < my) ? 1 : 0;
            if (rank < KNN) nn[rank] = (int)(my & 0xffffffffu);
        }
        __syncthreads();
    }

    if (tid < KNN) {
        const float4 qn = P[nn[tid]];
        const float vx = qn.x - p.x;
        const float vy = qn.y - p.y;
        const float vz = qn.z - p.z;
        const float den = sqrtf(vx * vx + vy * vy + vz * vz) + 1e-8f;
        uxs[tid] = vx / den; uys[tid] = vy / den; uzs[tid] = vz / den;
    }
    __syncthreads();

    if (tid < KNN * KNN) {
        const int k = tid / KNN, l = tid % KNN;
        float cc = uxs[k] * uxs[l] + uys[k] * uys[l] + uzs[k] * uzs[l];
        cc = fminf(fmaxf(cc, -1.0f), 1.0f);
        const float ang = acosf(cc);
        float q = rintf(ang * (float)(180.0 / (15.0 * M_PI)));
        q = fminf(fmaxf(q, 0.0f), 15.0f);
        atomicOr(&amask_s, 1u << (int)q);
    }
    __syncthreads();

    const unsigned am = amask_s;
    const int c7 = tid & 127;
    const int half = tid >> 7;
    float s = 0.0f;
    const float* tdc = Td + c7;
    #pragma unroll 4
    for (int v = half; v <= maxbin; v += 2) {
        s += (float)hist[v] * tdc[v * HID];
    }
    float mx = -FLT_MAX_;
    const float* tac = Ta + c7;
    #pragma unroll
    for (int v = 0; v < 8; ++v) {
        const int vv = half * 8 + v;
        const float tv = tac[vv * HID];
        if (am & (1u << vv)) mx = fmaxf(mx, tv);
    }
    sums[tid] = s;
    mxs[tid] = mx;
    __syncthreads();
    if (tid < HID) {
        out[(size_t)gid * HID + tid] =
            (sums[tid] + sums[tid + 128]) + fmaxf(mxs[tid], mxs[tid + 128]);
    }
}

extern "C" void kernel_launch(void* const* d_in, const int* in_sizes, int n_in,
                              void* d_out, int out_size, void* d_ws, size_t ws_size,
                              hipStream_t stream) {
    const float* pts = (const float*)d_in[0];
    const float* Wd  = (const float*)d_in[1];
    const float* bd  = (const float*)d_in[2];
    const float* Wa  = (const float*)d_in[3];
    const float* ba  = (const float*)d_in[4];
    float* out = (float*)d_out;

    const int B = in_sizes[0] / (NPTS * 3);
    const int nP = B * NPTS;

    float* Td = (float*)d_ws;                        // 256*128*4 = 128 KiB
    float* Ta = Td + 256 * HID;                      // 16*128*4  =   8 KiB
    float4* P4 = (float4*)(Ta + 16 * HID);           // nP*16 B

    gse_build<<<272, 512, 0, stream>>>(Wd, bd, Wa, ba, pts, nP, Td, Ta, P4);
    if (nP % PPB == 0) {
        gse_main2<<<nP / PPB, PPB * 256, 0, stream>>>(P4, Td, Ta, out);
    } else {
        gse_main<<<nP, 256, 0, stream>>>(P4, Td, Ta, out);
    }
}